// Round 8
// baseline (285.026 us; speedup 1.0000x reference)
//
#include <hip/hip_runtime.h>
#include <math.h>

#define N_SYM 128
#define BATCH 131072
#define B4    (BATCH / 4)   // row stride in float4 units = 32768
#define LEV   30.0f
#define D     4             // wave0 ring depth (R3-proven)
#define PD    8             // prefetch distance in symbols

typedef float v4 __attribute__((ext_vector_type(4)));

// R10: L2-warming prefetch waves around the proven R3 core.
// Ledger: every exchange/sync design (R4/R5/R6/R9: gload_lds or VGPR+LDS,
// barriered or free-running) = 107-120 us; free-running compiler-scheduled
// R3 = 76 us. R3's pacing: 285 cyc/req/wave => only ~3 reqs effectively in
// flight per wave at ~900 cyc HBM/L3 latency (ring D=4==D=8: per-wave
// in-flight is a HW/compiler artifact we can't widen). Untried lever:
// cut LATENCY. wave0 = byte-exact R3-D4 (bounded downside); waves 1-4
// prefetch one array each, <=PD symbols ahead (volatile LDS progress
// counter, lane0-written, no barrier, wave0 never waits), results kept
// alive via asm "v" (no store). HBM bytes NOT duplicated: pf pulls
// HBM/L3->L2 once, wave0 re-reads as ~200cyc L2 hits -> ~3-4x pacing.
// L2 footprint 64 blk/XCD x 8 sym x 4 KB = 2 MB < 4 MB.
__device__ __forceinline__ float step1(float f, float e, float p, float m,
                                       float st, float mn, float mx,
                                       float* um)
{
    const float mrl = m * LEV;
    const float us  = *um * mrl;                // unused_size
    const float mps = fabsf(p) + us;            // max_pos_size
    const float adj = fminf((p * f > 0.0f) ? us : mps, 0.0f);
    const float nps = f * (mps - adj);

    float       a  = fabsf(nps);
    const float sg = copysignf(1.0f, nps);
    a = floorf(a / st) * st;
    a = (a < mn) ? 0.0f : a;
    a = fminf(a, mx);

    *um = (mps - a) / mrl;
    return e * (sg * a) + (1.0f - e) * p;
}

__global__ __launch_bounds__(320) void lle_pf_kernel(
    const float* __restrict__ frac,
    const float* __restrict__ exs,
    const float* __restrict__ pos,
    const float* __restrict__ mrate,
    const float* __restrict__ um0,
    const float* __restrict__ msm_min,
    const float* __restrict__ msm_step,
    const float* __restrict__ msm_max,
    float* __restrict__ out)
{
    __shared__ volatile int prog;               // wave0's current symbol

    const int    wv   = threadIdx.x >> 6;
    const int    lane = threadIdx.x & 63;
    const size_t c4   = (size_t)blockIdx.x * 64 + lane;  // float4 col idx

    const v4* F = (const v4*)frac;
    const v4* E = (const v4*)exs;
    const v4* P = (const v4*)pos;
    const v4* M = (const v4*)mrate;
    v4*       O = (v4*)out;

    if (wv == 0) {
        // ================= wave 0: exact R3-D4 core =================
        if (lane == 0) prog = -1;

        const v4 umv = *((const v4*)um0 + c4);
        float um[4] = {umv.x, umv.y, umv.z, umv.w};

        v4 fb[D], eb[D], pb[D], mb[D];

        // warm the ring: symbols 0..D-1 (plain loads -> cache-friendly)
#pragma unroll
        for (int j = 0; j < D; ++j) {
            const size_t o = (size_t)j * B4 + c4;
            fb[j] = F[o]; eb[j] = E[o]; pb[j] = P[o]; mb[j] = M[o];
        }

        for (int s0 = 0; s0 < N_SYM - D; s0 += D) {
#pragma unroll
            for (int j = 0; j < D; ++j) {
                const int s = s0 + j;
                if (lane == 0) prog = s;        // throttle signal (no wait)
                const v4 f = fb[j];
                const v4 e = eb[j];
                const v4 p = pb[j];
                const v4 m = mb[j];

                {   // refill ring slot j with symbol s+D
                    const size_t o = (size_t)(s + D) * B4 + c4;
                    fb[j] = F[o]; eb[j] = E[o]; pb[j] = P[o]; mb[j] = M[o];
                }

                const float st = msm_step[s];   // uniform -> s_load
                const float mn = msm_min[s];
                const float mx = msm_max[s];

                v4 r;
                r.x = step1(f.x, e.x, p.x, m.x, st, mn, mx, &um[0]);
                r.y = step1(f.y, e.y, p.y, m.y, st, mn, mx, &um[1]);
                r.z = step1(f.z, e.z, p.z, m.z, st, mn, mx, &um[2]);
                r.w = step1(f.w, e.w, p.w, m.w, st, mn, mx, &um[3]);

                __builtin_nontemporal_store(r, O + (size_t)s * B4 + c4);
            }
        }

#pragma unroll
        for (int j = 0; j < D; ++j) {
            const int s = N_SYM - D + j;
            if (lane == 0) prog = s;
            const v4 f = fb[j];
            const v4 e = eb[j];
            const v4 p = pb[j];
            const v4 m = mb[j];

            const float st = msm_step[s];
            const float mn = msm_min[s];
            const float mx = msm_max[s];

            v4 r;
            r.x = step1(f.x, e.x, p.x, m.x, st, mn, mx, &um[0]);
            r.y = step1(f.y, e.y, p.y, m.y, st, mn, mx, &um[1]);
            r.z = step1(f.z, e.z, p.z, m.z, st, mn, mx, &um[2]);
            r.w = step1(f.w, e.w, p.w, m.w, st, mn, mx, &um[3]);

            __builtin_nontemporal_store(r, O + (size_t)s * B4 + c4);
        }

        v4 umo;
        umo.x = um[0]; umo.y = um[1]; umo.z = um[2]; umo.w = um[3];
        __builtin_nontemporal_store(umo, O + (size_t)N_SYM * B4 + c4);
    } else {
        // ============ waves 1-4: L2-warming prefetchers ============
        const v4* SRC = (wv == 1) ? F : (wv == 2) ? E : (wv == 3) ? P : M;

        __builtin_amdgcn_s_sleep(32);           // let wave0 init prog

        for (int g = 0; g < N_SYM / 4; ++g) {
            const int s = g * 4;
            // stay <= PD symbols ahead of wave0; wave0 NEVER waits on us
            while (s > prog + PD) __builtin_amdgcn_s_sleep(8);

            const v4 a = SRC[(size_t)(s + 0) * B4 + c4];
            const v4 b = SRC[(size_t)(s + 1) * B4 + c4];
            const v4 c = SRC[(size_t)(s + 2) * B4 + c4];
            const v4 d = SRC[(size_t)(s + 3) * B4 + c4];
            // keep loads live without a store (guide rule #17)
            asm volatile("" :: "v"(a), "v"(b), "v"(c), "v"(d));
        }
    }
}

extern "C" void kernel_launch(void* const* d_in, const int* in_sizes, int n_in,
                              void* d_out, int out_size, void* d_ws, size_t ws_size,
                              hipStream_t stream) {
    const float* frac     = (const float*)d_in[0];
    const float* exs      = (const float*)d_in[1];
    const float* pos      = (const float*)d_in[2];
    const float* mrate    = (const float*)d_in[3];
    const float* um0      = (const float*)d_in[4];
    const float* msm_min  = (const float*)d_in[5];
    const float* msm_step = (const float*)d_in[6];
    const float* msm_max  = (const float*)d_in[7];
    float* out = (float*)d_out;

    const int block = 320;                 // wave0 = R3 core + 4 pf waves
    const int grid  = (BATCH / 4) / 64;    // 512 blocks -> 2/CU, 10 waves/CU

    hipLaunchKernelGGL(lle_pf_kernel, dim3(grid), dim3(block), 0, stream,
                       frac, exs, pos, mrate, um0, msm_min, msm_step, msm_max,
                       out);
}

// Round 9
// 282.957 us; speedup vs baseline: 1.0073x; 1.0073x over previous
//
#include <hip/hip_runtime.h>
#include <math.h>

#define N_SYM 128
#define BATCH 131072
#define B4    (BATCH / 4)   // row stride in float4 units = 32768
#define LEV   30.0f
#define D     4             // wave0 ring depth (R3-proven)
#define PD    8             // prefetch lead in symbols (L2 budget: 3 MB/XCD)

typedef float v4 __attribute__((ext_vector_type(4)));

// R11 = R10 with the compiler-hostility removed.
// R10's VGPR_Count=56 proved the compiler destroyed wave0's 16-slot ring
// (needs ~88 VGPR): the exec-masked VOLATILE LDS write inside the unrolled
// hot loop split scheduling regions and pinned code motion -> refill loads
// sank to use -> latency-serial wave0 (133us). The prefetch theory was
// never measured. Changes:
//  1. throttle write hoisted to the OUTER loop (once per D symbols) as a
//     RELAXED LDS atomic (plain ds_write_b32, no volatile fences);
//  2. inner loop now structurally identical to R3's (validity gate:
//     VGPR must return to ~88);
//  3. PD=8 (lead <= PD+D symbols -> 64blk/XCD x 12 x 4KB = 3MB < 4MB L2).
// Model: per-wave issue pacing caps R3 at 17 Mreq/s/CU of ~25 (miss-path
// service cap; L2 hits are NOT capped -- m56 = 144 GB/s/CU). pf waves
// (one array each, free-running, throttled to <=PD ahead) move wave0's
// refills onto the L2-hit path: shorter latency AND off the capped path.
__device__ __forceinline__ float step1(float f, float e, float p, float m,
                                       float st, float mn, float mx,
                                       float* um)
{
    const float mrl = m * LEV;
    const float us  = *um * mrl;                // unused_size
    const float mps = fabsf(p) + us;            // max_pos_size
    const float adj = fminf((p * f > 0.0f) ? us : mps, 0.0f);
    const float nps = f * (mps - adj);

    float       a  = fabsf(nps);
    const float sg = copysignf(1.0f, nps);
    a = floorf(a / st) * st;
    a = (a < mn) ? 0.0f : a;
    a = fminf(a, mx);

    *um = (mps - a) / mrl;
    return e * (sg * a) + (1.0f - e) * p;
}

__global__ __launch_bounds__(320) void lle_pf2_kernel(
    const float* __restrict__ frac,
    const float* __restrict__ exs,
    const float* __restrict__ pos,
    const float* __restrict__ mrate,
    const float* __restrict__ um0,
    const float* __restrict__ msm_min,
    const float* __restrict__ msm_step,
    const float* __restrict__ msm_max,
    float* __restrict__ out)
{
    __shared__ int prog;                        // wave0 progress (symbols)

    const int    wv   = threadIdx.x >> 6;
    const int    lane = threadIdx.x & 63;
    const size_t c4   = (size_t)blockIdx.x * 64 + lane;  // float4 col idx

    const v4* F = (const v4*)frac;
    const v4* E = (const v4*)exs;
    const v4* P = (const v4*)pos;
    const v4* M = (const v4*)mrate;
    v4*       O = (v4*)out;

    if (wv == 0) {
        // ================= wave 0: exact R3-D4 core =================
        if (lane == 0)
            __hip_atomic_store(&prog, -1, __ATOMIC_RELAXED,
                               __HIP_MEMORY_SCOPE_WORKGROUP);

        const v4 umv = *((const v4*)um0 + c4);
        float um[4] = {umv.x, umv.y, umv.z, umv.w};

        v4 fb[D], eb[D], pb[D], mb[D];

        // warm the ring: symbols 0..D-1
#pragma unroll
        for (int j = 0; j < D; ++j) {
            const size_t o = (size_t)j * B4 + c4;
            fb[j] = F[o]; eb[j] = E[o]; pb[j] = P[o]; mb[j] = M[o];
        }

        for (int s0 = 0; s0 < N_SYM - D; s0 += D) {
            // throttle signal: OUTSIDE the unrolled body, relaxed, no fence
            if (lane == 0)
                __hip_atomic_store(&prog, s0, __ATOMIC_RELAXED,
                                   __HIP_MEMORY_SCOPE_WORKGROUP);
#pragma unroll
            for (int j = 0; j < D; ++j) {
                const int s = s0 + j;
                const v4 f = fb[j];
                const v4 e = eb[j];
                const v4 p = pb[j];
                const v4 m = mb[j];

                {   // refill ring slot j with symbol s+D
                    const size_t o = (size_t)(s + D) * B4 + c4;
                    fb[j] = F[o]; eb[j] = E[o]; pb[j] = P[o]; mb[j] = M[o];
                }

                const float st = msm_step[s];   // uniform -> s_load
                const float mn = msm_min[s];
                const float mx = msm_max[s];

                v4 r;
                r.x = step1(f.x, e.x, p.x, m.x, st, mn, mx, &um[0]);
                r.y = step1(f.y, e.y, p.y, m.y, st, mn, mx, &um[1]);
                r.z = step1(f.z, e.z, p.z, m.z, st, mn, mx, &um[2]);
                r.w = step1(f.w, e.w, p.w, m.w, st, mn, mx, &um[3]);

                __builtin_nontemporal_store(r, O + (size_t)s * B4 + c4);
            }
        }

        // peeled tail: last D symbols, no refill
#pragma unroll
        for (int j = 0; j < D; ++j) {
            const int s = N_SYM - D + j;
            const v4 f = fb[j];
            const v4 e = eb[j];
            const v4 p = pb[j];
            const v4 m = mb[j];

            const float st = msm_step[s];
            const float mn = msm_min[s];
            const float mx = msm_max[s];

            v4 r;
            r.x = step1(f.x, e.x, p.x, m.x, st, mn, mx, &um[0]);
            r.y = step1(f.y, e.y, p.y, m.y, st, mn, mx, &um[1]);
            r.z = step1(f.z, e.z, p.z, m.z, st, mn, mx, &um[2]);
            r.w = step1(f.w, e.w, p.w, m.w, st, mn, mx, &um[3]);

            __builtin_nontemporal_store(r, O + (size_t)s * B4 + c4);
        }

        v4 umo;
        umo.x = um[0]; umo.y = um[1]; umo.z = um[2]; umo.w = um[3];
        __builtin_nontemporal_store(umo, O + (size_t)N_SYM * B4 + c4);
    } else {
        // ============ waves 1-4: L2-warming prefetchers ============
        // each handles ONE array; throttled to <= PD+D symbols ahead of
        // wave0's consumption; results discarded (kept live via asm).
        const v4* SRC = (wv == 1) ? F : (wv == 2) ? E : (wv == 3) ? P : M;

        __builtin_amdgcn_s_sleep(32);           // let wave0 init prog

        for (int g = 0; g < N_SYM / 4; ++g) {
            const int s = g * 4;
            // wave0 is consuming ~prog..prog+D; stay <= PD past the ring
            while (s > __hip_atomic_load(&prog, __ATOMIC_RELAXED,
                                         __HIP_MEMORY_SCOPE_WORKGROUP) + PD)
                __builtin_amdgcn_s_sleep(8);

            const v4 a = SRC[(size_t)(s + 0) * B4 + c4];
            const v4 b = SRC[(size_t)(s + 1) * B4 + c4];
            const v4 c = SRC[(size_t)(s + 2) * B4 + c4];
            const v4 d = SRC[(size_t)(s + 3) * B4 + c4];
            asm volatile("" :: "v"(a), "v"(b), "v"(c), "v"(d));
        }
    }
}

extern "C" void kernel_launch(void* const* d_in, const int* in_sizes, int n_in,
                              void* d_out, int out_size, void* d_ws, size_t ws_size,
                              hipStream_t stream) {
    const float* frac     = (const float*)d_in[0];
    const float* exs      = (const float*)d_in[1];
    const float* pos      = (const float*)d_in[2];
    const float* mrate    = (const float*)d_in[3];
    const float* um0      = (const float*)d_in[4];
    const float* msm_min  = (const float*)d_in[5];
    const float* msm_step = (const float*)d_in[6];
    const float* msm_max  = (const float*)d_in[7];
    float* out = (float*)d_out;

    const int block = 320;                 // wave0 = R3 core + 4 pf waves
    const int grid  = (BATCH / 4) / 64;    // 512 blocks -> 2/CU, 10 waves/CU

    hipLaunchKernelGGL(lle_pf2_kernel, dim3(grid), dim3(block), 0, stream,
                       frac, exs, pos, mrate, um0, msm_min, msm_step, msm_max,
                       out);
}